// Round 7
// baseline (326.748 us; speedup 1.0000x reference)
//
#include <hip/hip_runtime.h>

#define NCH 32          // channels
#define GROUPS 8        // float4 groups per row (32 / 4)
#define KVOL 27         // 3^3 kernel offsets
#define LG 100          // grid side
#define LP 102          // padded side (1-cell zero ring)
#define RGN 5           // region side per block
#define NRGN 20         // LG / RGN
#define NREGIONS (NRGN * NRGN * NRGN)   // 8000
#define BSIDE 7         // RGN + 2
#define BVOL 343        // brick cells
#define CELLS 125       // RGN^3
#define LSTR 28         // per-cell LDS tap stride (max 27, mult of 4)
#define DUMMY 27        // (row 0 << 5) | k=27 -> feats[0] * zero weight
#define SLOTS 32        // output rows per gather block

static __device__ __forceinline__ void fma4(float4& a, float4 f, float4 w) {
    a.x += f.x * w.x; a.y += f.y * w.y; a.z += f.z * w.z; a.w += f.w * w.w;
}

// ---- Kernel 1: padded dense presence map: dense[flatp] = row+1 --------------
__global__ void build_dense(const int* __restrict__ coords,
                            int* __restrict__ dense, int N) {
    int i = blockIdx.x * blockDim.x + threadIdx.x;
    if (i >= N) return;
    int x = coords[3 * i + 0];
    int y = coords[3 * i + 1];
    int z = coords[3 * i + 2];
    dense[((size_t)(x + 1) * LP + (y + 1)) * LP + (z + 1)] = i + 1;
}

// ---- Kernel 2 (Phase A): per-region compaction -> global row/tap lists ------
__global__ __launch_bounds__(256) void compact_region(
        const int* __restrict__ dense,
        int* __restrict__ gctr,      // [0]=row alloc, [1]=tap alloc
        int* __restrict__ rows_g,    // [N] output row per slot
        int* __restrict__ offcnt_g,  // [N] (tap_off<<3) | (jend>>2)
        int* __restrict__ list_g) {  // packed taps (vrow<<5)|k
    __shared__ int brick[BVOL];
    __shared__ int rows_l[CELLS], offs_l[CELLS], cnts_l[CELLS];
    __shared__ int lds_list[CELLS * LSTR];     // 14 KB
    __shared__ int cnt, taptot, rowbase, tapbase;

    int tid = threadIdx.x;
    int r = blockIdx.x;
    if (tid == 0) { cnt = 0; taptot = 0; }

    int bx = r / (NRGN * NRGN);
    int by = (r / NRGN) % NRGN;
    int bz = r % NRGN;
    int ox = bx * RGN, oy = by * RGN, oz = bz * RGN;

    for (int i = tid; i < BVOL; i += 256) {
        int lx = i / (BSIDE * BSIDE), ly = (i / BSIDE) % BSIDE, lz = i % BSIDE;
        brick[i] = dense[((size_t)(ox + lx) * LP + (oy + ly)) * LP + (oz + lz)];
    }
    __syncthreads();

    if (tid < CELLS) {
        int cx = tid / (RGN * RGN), cy = (tid / RGN) % RGN, cz = tid % RGN;
        int bidx = (cx + 1) * (BSIDE * BSIDE) + (cy + 1) * BSIDE + (cz + 1);
        int v = brick[bidx];
        if (v > 0) {
            int p = atomicAdd(&cnt, 1);
            rows_l[p] = v - 1;
            int j = 0;
            #pragma unroll
            for (int k = 0; k < KVOL; ++k) {   // folds to const brick offsets
                int dx = k / 9 - 1, dy = (k / 3) % 3 - 1, dz = k % 3 - 1;
                int nb = brick[bidx + dx * (BSIDE * BSIDE) + dy * BSIDE + dz];
                if (nb > 0) lds_list[p * LSTR + (j++)] = ((nb - 1) << 5) | k;
            }
            while (j & 3) lds_list[p * LSTR + (j++)] = DUMMY;  // pad to x4
            cnts_l[p] = j;
            offs_l[p] = atomicAdd(&taptot, j);
        }
    }
    __syncthreads();

    if (tid == 0) {
        rowbase = atomicAdd(&gctr[0], cnt);
        tapbase = atomicAdd(&gctr[1], taptot);
    }
    __syncthreads();

    if (tid < cnt) {
        int off = tapbase + offs_l[tid];
        int jend = cnts_l[tid];
        rows_g[rowbase + tid] = rows_l[tid];
        offcnt_g[rowbase + tid] = (off << 3) | (jend >> 2);
        for (int j = 0; j < jend; ++j)
            list_g[off + j] = lds_list[tid * LSTR + j];
    }
}

// ---- Kernel 3 (Phase B): flat gather — full slots, no barriers --------------
__global__ __launch_bounds__(256) void gather_flat(
        const int* __restrict__ rows_g,
        const int* __restrict__ offcnt_g,
        const int* __restrict__ list_g,
        const float4* __restrict__ in_feats4,
        const float4* __restrict__ kernel4,
        float4* __restrict__ out4,
        int Nrows) {
    __shared__ float4 kw[(KVOL + 1) * GROUPS];  // row 27 = zeros
    int tid = threadIdx.x;
    for (int i = tid; i < (KVOL + 1) * GROUPS; i += 256)
        kw[i] = (i < KVOL * GROUPS) ? kernel4[i]
                                    : make_float4(0.f, 0.f, 0.f, 0.f);
    __syncthreads();

    int sid = blockIdx.x * SLOTS + (tid >> 3);
    int g   = tid & 7;
    if (sid >= Nrows) return;

    int row  = rows_g[sid];
    int oc   = offcnt_g[sid];
    int nq   = oc & 7;                        // jend/4, in [1,7]
    const int4* tl = (const int4*)(list_g + (oc >> 3));

    float4 acc = make_float4(0.f, 0.f, 0.f, 0.f);
    for (int jq = 0; jq < nq; ++jq) {
        int4 t = tl[jq];                       // L1-broadcast across 8 g-lanes
        float4 f0 = in_feats4[(size_t)(t.x >> 5) * GROUPS + g];
        float4 f1 = in_feats4[(size_t)(t.y >> 5) * GROUPS + g];
        float4 f2 = in_feats4[(size_t)(t.z >> 5) * GROUPS + g];
        float4 f3 = in_feats4[(size_t)(t.w >> 5) * GROUPS + g];
        float4 w0 = kw[(t.x & 31) * GROUPS + g];
        float4 w1 = kw[(t.y & 31) * GROUPS + g];
        float4 w2 = kw[(t.z & 31) * GROUPS + g];
        float4 w3 = kw[(t.w & 31) * GROUPS + g];
        fma4(acc, f0, w0); fma4(acc, f1, w1);
        fma4(acc, f2, w2); fma4(acc, f3, w3);
    }
    out4[(size_t)row * GROUPS + g] = acc;
}

// ---- Mid fallback: R5 single-phase region kernel ----------------------------
#define LSTR5 29
__global__ __launch_bounds__(256) void gather_conv_region(
        const int* __restrict__ dense,
        const float4* __restrict__ in_feats4,
        const float4* __restrict__ kernel4,
        float4* __restrict__ out4) {
    __shared__ float4 kw[(KVOL + 1) * GROUPS];
    __shared__ int brick[BVOL];
    __shared__ int rows[CELLS];
    __shared__ int cnts[CELLS];
    __shared__ int list[CELLS * LSTR5];
    __shared__ int cnt;

    int tid = threadIdx.x;
    int r = blockIdx.x;
    if (tid == 0) cnt = 0;
    for (int i = tid; i < (KVOL + 1) * GROUPS; i += 256)
        kw[i] = (i < KVOL * GROUPS) ? kernel4[i]
                                    : make_float4(0.f, 0.f, 0.f, 0.f);
    int bx = r / (NRGN * NRGN);
    int by = (r / NRGN) % NRGN;
    int bz = r % NRGN;
    int ox = bx * RGN, oy = by * RGN, oz = bz * RGN;
    for (int i = tid; i < BVOL; i += 256) {
        int lx = i / (BSIDE * BSIDE), ly = (i / BSIDE) % BSIDE, lz = i % BSIDE;
        brick[i] = dense[((size_t)(ox + lx) * LP + (oy + ly)) * LP + (oz + lz)];
    }
    __syncthreads();
    if (tid < CELLS) {
        int cx = tid / (RGN * RGN), cy = (tid / RGN) % RGN, cz = tid % RGN;
        int bidx = (cx + 1) * (BSIDE * BSIDE) + (cy + 1) * BSIDE + (cz + 1);
        int v = brick[bidx];
        if (v > 0) {
            int p = atomicAdd(&cnt, 1);
            rows[p] = v - 1;
            int j = 0;
            #pragma unroll
            for (int k = 0; k < KVOL; ++k) {
                int dx = k / 9 - 1, dy = (k / 3) % 3 - 1, dz = k % 3 - 1;
                int nb = brick[bidx + dx * (BSIDE * BSIDE) + dy * BSIDE + dz];
                if (nb > 0) list[p * LSTR5 + (j++)] = ((nb - 1) << 5) | k;
            }
            while (j & 3) list[p * LSTR5 + (j++)] = DUMMY;
            cnts[p] = j;
        }
    }
    __syncthreads();
    int n = cnt, lr = tid >> 3, g = tid & 7;
    for (int base = 0; base < n; base += 32) {
        int lo = base + lr;
        if (lo < n) {
            int jend = cnts[lo];
            const int* tl = &list[lo * LSTR5];
            float4 acc = make_float4(0.f, 0.f, 0.f, 0.f);
            for (int j = 0; j < jend; j += 4) {
                int e0 = tl[j], e1 = tl[j+1], e2 = tl[j+2], e3 = tl[j+3];
                float4 f0 = in_feats4[(size_t)(e0 >> 5) * GROUPS + g];
                float4 f1 = in_feats4[(size_t)(e1 >> 5) * GROUPS + g];
                float4 f2 = in_feats4[(size_t)(e2 >> 5) * GROUPS + g];
                float4 f3 = in_feats4[(size_t)(e3 >> 5) * GROUPS + g];
                fma4(acc, f0, kw[(e0 & 31) * GROUPS + g]);
                fma4(acc, f1, kw[(e1 & 31) * GROUPS + g]);
                fma4(acc, f2, kw[(e2 & 31) * GROUPS + g]);
                fma4(acc, f3, kw[(e3 & 31) * GROUPS + g]);
            }
            out4[(size_t)rows[lo] * GROUPS + g] = acc;
        }
    }
}

// ---- Last-resort fallback: atomic scatter -----------------------------------
__global__ void mink_conv_scatter(const int* __restrict__ coords,
                                  const int* __restrict__ in_idx,
                                  const int* __restrict__ out_idx,
                                  const float4* __restrict__ in_feats4,
                                  const float4* __restrict__ kernel4,
                                  float* __restrict__ out,
                                  int E) {
    __shared__ float4 kwf[KVOL * GROUPS];
    for (int i = threadIdx.x; i < KVOL * GROUPS; i += blockDim.x)
        kwf[i] = kernel4[i];
    __syncthreads();
    int t = blockIdx.x * blockDim.x + threadIdx.x;
    if (t >= E * GROUPS) return;
    int e = t >> 3, g = t & 7;
    int vi = in_idx[e], vo = out_idx[e];
    int c0 = coords[vi * 3 + 0] - coords[vo * 3 + 0] + 1;
    int c1 = coords[vi * 3 + 1] - coords[vo * 3 + 1] + 1;
    int c2 = coords[vi * 3 + 2] - coords[vo * 3 + 2] + 1;
    int k1d = (c0 * 3 + c1) * 3 + c2;
    float4 f = in_feats4[vi * GROUPS + g];
    float4 w = kwf[k1d * GROUPS + g];
    float* o = out + vo * NCH + g * 4;
    atomicAdd(o + 0, f.x * w.x);
    atomicAdd(o + 1, f.y * w.y);
    atomicAdd(o + 2, f.z * w.z);
    atomicAdd(o + 3, f.w * w.w);
}

static inline size_t align256(size_t x) { return (x + 255) & ~(size_t)255; }

extern "C" void kernel_launch(void* const* d_in, const int* in_sizes, int n_in,
                              void* d_out, int out_size, void* d_ws, size_t ws_size,
                              hipStream_t stream) {
    const int*   coords   = (const int*)d_in[0];
    const int*   in_idx   = (const int*)d_in[1];
    const int*   out_idx  = (const int*)d_in[2];
    const float* in_feats = (const float*)d_in[3];
    const float* kernel   = (const float*)d_in[4];

    const int E     = in_sizes[1];
    const int Nrows = out_size / NCH;

    const size_t dense_bytes = (size_t)LP * LP * LP * sizeof(int); // 4.25 MB

    // Workspace layout for the two-phase path
    size_t o_dense  = 0;
    size_t o_gctr   = align256(o_dense + dense_bytes);
    size_t o_rows   = align256(o_gctr + 256);
    size_t o_offcnt = align256(o_rows + (size_t)Nrows * 4);
    size_t o_list   = align256(o_offcnt + (size_t)Nrows * 4);
    size_t list_cap = ((size_t)E + 3ull * Nrows + 4096) * 4;  // pad-to-4 bound
    size_t need2    = o_list + list_cap;

    char* ws = (char*)d_ws;

    if (ws_size >= need2) {
        int* dense  = (int*)(ws + o_dense);
        int* gctr   = (int*)(ws + o_gctr);
        int* rows_g = (int*)(ws + o_rows);
        int* offcnt = (int*)(ws + o_offcnt);
        int* list_g = (int*)(ws + o_list);

        hipMemsetAsync(dense, 0, dense_bytes, stream);
        hipMemsetAsync(gctr, 0, 256, stream);

        int block = 256;
        int grid1 = (Nrows + block - 1) / block;
        build_dense<<<grid1, block, 0, stream>>>(coords, dense, Nrows);

        compact_region<<<NREGIONS, 256, 0, stream>>>(
            dense, gctr, rows_g, offcnt, list_g);

        int grid3 = (Nrows + SLOTS - 1) / SLOTS;
        gather_flat<<<grid3, 256, 0, stream>>>(
            rows_g, offcnt, list_g,
            (const float4*)in_feats, (const float4*)kernel,
            (float4*)d_out, Nrows);
    } else if (ws_size >= dense_bytes) {
        int* dense = (int*)d_ws;
        hipMemsetAsync(dense, 0, dense_bytes, stream);
        int block = 256;
        int grid1 = (Nrows + block - 1) / block;
        build_dense<<<grid1, block, 0, stream>>>(coords, dense, Nrows);
        gather_conv_region<<<NREGIONS, 256, 0, stream>>>(
            dense, (const float4*)in_feats, (const float4*)kernel,
            (float4*)d_out);
    } else {
        hipMemsetAsync(d_out, 0, (size_t)out_size * sizeof(float), stream);
        int total = E * GROUPS;
        int block = 256;
        int grid  = (total + block - 1) / block;
        mink_conv_scatter<<<grid, block, 0, stream>>>(
            coords, in_idx, out_idx,
            (const float4*)in_feats, (const float4*)kernel,
            (float*)d_out, E);
    }
}

// Round 8
// 167.965 us; speedup vs baseline: 1.9453x; 1.9453x over previous
//
#include <hip/hip_runtime.h>

#define NCH 32          // channels
#define GROUPS 8        // float4 groups per row (32 / 4)
#define KVOL 27         // 3^3 kernel offsets
#define LG 100          // grid side
#define LP 102          // padded side (1-cell zero ring)
#define RGN 5           // region side per block
#define NRGN 20         // LG / RGN
#define NREGIONS (NRGN * NRGN * NRGN)   // 8000
#define BSIDE 7         // RGN + 2
#define BVOL 343        // brick cells
#define CELLS 125       // RGN^3
#define DUMMY 27        // (row 0 << 5) | k=27 -> feats[0] * zero weight
#define SLOTS 32        // output rows per gather block
#define ARENAS 64
#define REG_PER_ARENA (NREGIONS / ARENAS)   // 125 contiguous regions/arena
#define GSTR 16         // gctr stride in ulonglong (128 B -> no line sharing)
#define LCAP 4096       // LDS tap-list cap (max physical 125*32 = 4000)

static __device__ __forceinline__ void fma4(float4& a, float4 f, float4 w) {
    a.x += f.x * w.x; a.y += f.y * w.y; a.z += f.z * w.z; a.w += f.w * w.w;
}

// ---- Kernel 1: padded dense presence map: dense[flatp] = row+1 --------------
__global__ void build_dense(const int* __restrict__ coords,
                            int* __restrict__ dense, int N) {
    int i = blockIdx.x * blockDim.x + threadIdx.x;
    if (i >= N) return;
    int x = coords[3 * i + 0];
    int y = coords[3 * i + 1];
    int z = coords[3 * i + 2];
    dense[((size_t)(x + 1) * LP + (y + 1)) * LP + (z + 1)] = i + 1;
}

// ---- Kernel 2 (Phase A): region compaction -> arena-striped global lists ----
__global__ __launch_bounds__(256) void compact_region(
        const int* __restrict__ dense,
        unsigned long long* __restrict__ gctr,  // [ARENAS*GSTR] packed cnt|taps
        int* __restrict__ rows_g,               // [ARENAS*rowcap]
        int* __restrict__ offcnt_g,             // [ARENAS*rowcap] (off<<3)|(jend>>3)
        int* __restrict__ list_g,               // [ARENAS*tapcap] (vrow<<5)|k
        int rowcap, int tapcap) {
    __shared__ int brick[BVOL];
    __shared__ int rows_l[CELLS], offs_l[CELLS], cnts_l[CELLS];
    __shared__ int lds_list[LCAP];
    __shared__ int cnt, taptot;
    __shared__ unsigned long long basepack;

    int tid = threadIdx.x;
    int r = blockIdx.x;
    int arena = r / REG_PER_ARENA;     // contiguous slabs -> locality preserved
    if (tid == 0) { cnt = 0; taptot = 0; }

    int bx = r / (NRGN * NRGN);
    int by = (r / NRGN) % NRGN;
    int bz = r % NRGN;
    int ox = bx * RGN, oy = by * RGN, oz = bz * RGN;

    for (int i = tid; i < BVOL; i += 256) {
        int lx = i / (BSIDE * BSIDE), ly = (i / BSIDE) % BSIDE, lz = i % BSIDE;
        brick[i] = dense[((size_t)(ox + lx) * LP + (oy + ly)) * LP + (oz + lz)];
    }
    __syncthreads();

    if (tid < CELLS) {
        int cx = tid / (RGN * RGN), cy = (tid / RGN) % RGN, cz = tid % RGN;
        int bidx = (cx + 1) * (BSIDE * BSIDE) + (cy + 1) * BSIDE + (cz + 1);
        int v = brick[bidx];
        if (v > 0) {
            // pass 1: count valid taps
            int j = 0;
            #pragma unroll
            for (int k = 0; k < KVOL; ++k) {
                int dx = k / 9 - 1, dy = (k / 3) % 3 - 1, dz = k % 3 - 1;
                if (brick[bidx + dx * (BSIDE * BSIDE) + dy * BSIDE + dz] > 0) j++;
            }
            int jpad = (j + 7) & ~7;                 // pad to x8 for MLP-8
            int p   = atomicAdd(&cnt, 1);            // LDS atomics: cheap
            int off = atomicAdd(&taptot, jpad);
            rows_l[p] = v - 1;
            offs_l[p] = off;
            cnts_l[p] = jpad;
            // pass 2: emit taps
            int w = off;
            #pragma unroll
            for (int k = 0; k < KVOL; ++k) {
                int dx = k / 9 - 1, dy = (k / 3) % 3 - 1, dz = k % 3 - 1;
                int nb = brick[bidx + dx * (BSIDE * BSIDE) + dy * BSIDE + dz];
                if (nb > 0) lds_list[w++] = ((nb - 1) << 5) | k;
            }
            while (w < off + jpad) lds_list[w++] = DUMMY;
        }
    }
    __syncthreads();

    if (tid == 0) {
        // ONE packed atomic per block, striped across 64 cache lines
        basepack = atomicAdd(&gctr[arena * GSTR],
                             ((unsigned long long)cnt << 32) |
                             (unsigned long long)(unsigned)taptot);
    }
    __syncthreads();

    int rowbase = (int)(basepack >> 32);
    int tapbase = (int)(basepack & 0xffffffffu);

    // coalesced list write-out by all 256 threads
    int* ldst = list_g + (size_t)arena * tapcap + tapbase;
    int tt = taptot;
    for (int i = tid; i < tt; i += 256) ldst[i] = lds_list[i];

    if (tid < cnt) {
        int gi = arena * rowcap + rowbase + tid;
        rows_g[gi]   = rows_l[tid];
        offcnt_g[gi] = ((tapbase + offs_l[tid]) << 3) | (cnts_l[tid] >> 3);
    }
}

// ---- Kernel 3 (Phase B): flat gather — full slots, no barriers, MLP-8 -------
__global__ __launch_bounds__(256) void gather_flat(
        const unsigned long long* __restrict__ gctr,
        const int* __restrict__ rows_g,
        const int* __restrict__ offcnt_g,
        const int* __restrict__ list_g,
        const float4* __restrict__ in_feats4,
        const float4* __restrict__ kernel4,
        float4* __restrict__ out4,
        int rowcap, int tapcap) {
    __shared__ float4 kw[(KVOL + 1) * GROUPS];  // row 27 = zeros
    int tid = threadIdx.x;
    for (int i = tid; i < (KVOL + 1) * GROUPS; i += 256)
        kw[i] = (i < KVOL * GROUPS) ? kernel4[i]
                                    : make_float4(0.f, 0.f, 0.f, 0.f);
    __syncthreads();

    int arena = blockIdx.y;
    int cnt_a = (int)(gctr[arena * GSTR] >> 32);
    int slot0 = blockIdx.x * SLOTS;
    if (slot0 >= cnt_a) return;                 // uniform early exit

    int sid = slot0 + (tid >> 3);
    int g   = tid & 7;
    if (sid >= cnt_a) return;

    int gi  = arena * rowcap + sid;
    int row = rows_g[gi];
    int oc  = offcnt_g[gi];
    int n8  = oc & 7;                           // jend/8, in [1,4]
    const int4* tl = (const int4*)(list_g + (size_t)arena * tapcap + (oc >> 3));

    float4 acc = make_float4(0.f, 0.f, 0.f, 0.f);
    for (int q = 0; q < n8; ++q) {
        int4 ta = tl[2 * q + 0];
        int4 tb = tl[2 * q + 1];
        float4 f0 = in_feats4[(size_t)(ta.x >> 5) * GROUPS + g];
        float4 f1 = in_feats4[(size_t)(ta.y >> 5) * GROUPS + g];
        float4 f2 = in_feats4[(size_t)(ta.z >> 5) * GROUPS + g];
        float4 f3 = in_feats4[(size_t)(ta.w >> 5) * GROUPS + g];
        float4 f4 = in_feats4[(size_t)(tb.x >> 5) * GROUPS + g];
        float4 f5 = in_feats4[(size_t)(tb.y >> 5) * GROUPS + g];
        float4 f6 = in_feats4[(size_t)(tb.z >> 5) * GROUPS + g];
        float4 f7 = in_feats4[(size_t)(tb.w >> 5) * GROUPS + g];
        fma4(acc, f0, kw[(ta.x & 31) * GROUPS + g]);
        fma4(acc, f1, kw[(ta.y & 31) * GROUPS + g]);
        fma4(acc, f2, kw[(ta.z & 31) * GROUPS + g]);
        fma4(acc, f3, kw[(ta.w & 31) * GROUPS + g]);
        fma4(acc, f4, kw[(tb.x & 31) * GROUPS + g]);
        fma4(acc, f5, kw[(tb.y & 31) * GROUPS + g]);
        fma4(acc, f6, kw[(tb.z & 31) * GROUPS + g]);
        fma4(acc, f7, kw[(tb.w & 31) * GROUPS + g]);
    }
    out4[(size_t)row * GROUPS + g] = acc;
}

// ---- Mid fallback: R5-style single-phase region kernel ----------------------
#define LSTR5 29
__global__ __launch_bounds__(256) void gather_conv_region(
        const int* __restrict__ dense,
        const float4* __restrict__ in_feats4,
        const float4* __restrict__ kernel4,
        float4* __restrict__ out4) {
    __shared__ float4 kw[(KVOL + 1) * GROUPS];
    __shared__ int brick[BVOL];
    __shared__ int rows[CELLS];
    __shared__ int cnts[CELLS];
    __shared__ int list[CELLS * LSTR5];
    __shared__ int cnt;

    int tid = threadIdx.x;
    int r = blockIdx.x;
    if (tid == 0) cnt = 0;
    for (int i = tid; i < (KVOL + 1) * GROUPS; i += 256)
        kw[i] = (i < KVOL * GROUPS) ? kernel4[i]
                                    : make_float4(0.f, 0.f, 0.f, 0.f);
    int bx = r / (NRGN * NRGN);
    int by = (r / NRGN) % NRGN;
    int bz = r % NRGN;
    int ox = bx * RGN, oy = by * RGN, oz = bz * RGN;
    for (int i = tid; i < BVOL; i += 256) {
        int lx = i / (BSIDE * BSIDE), ly = (i / BSIDE) % BSIDE, lz = i % BSIDE;
        brick[i] = dense[((size_t)(ox + lx) * LP + (oy + ly)) * LP + (oz + lz)];
    }
    __syncthreads();
    if (tid < CELLS) {
        int cx = tid / (RGN * RGN), cy = (tid / RGN) % RGN, cz = tid % RGN;
        int bidx = (cx + 1) * (BSIDE * BSIDE) + (cy + 1) * BSIDE + (cz + 1);
        int v = brick[bidx];
        if (v > 0) {
            int p = atomicAdd(&cnt, 1);
            rows[p] = v - 1;
            int j = 0;
            #pragma unroll
            for (int k = 0; k < KVOL; ++k) {
                int dx = k / 9 - 1, dy = (k / 3) % 3 - 1, dz = k % 3 - 1;
                int nb = brick[bidx + dx * (BSIDE * BSIDE) + dy * BSIDE + dz];
                if (nb > 0) list[p * LSTR5 + (j++)] = ((nb - 1) << 5) | k;
            }
            while (j & 3) list[p * LSTR5 + (j++)] = DUMMY;
            cnts[p] = j;
        }
    }
    __syncthreads();
    int n = cnt, lr = tid >> 3, g = tid & 7;
    for (int base = 0; base < n; base += 32) {
        int lo = base + lr;
        if (lo < n) {
            int jend = cnts[lo];
            const int* tl = &list[lo * LSTR5];
            float4 acc = make_float4(0.f, 0.f, 0.f, 0.f);
            for (int j = 0; j < jend; j += 4) {
                int e0 = tl[j], e1 = tl[j+1], e2 = tl[j+2], e3 = tl[j+3];
                float4 f0 = in_feats4[(size_t)(e0 >> 5) * GROUPS + g];
                float4 f1 = in_feats4[(size_t)(e1 >> 5) * GROUPS + g];
                float4 f2 = in_feats4[(size_t)(e2 >> 5) * GROUPS + g];
                float4 f3 = in_feats4[(size_t)(e3 >> 5) * GROUPS + g];
                fma4(acc, f0, kw[(e0 & 31) * GROUPS + g]);
                fma4(acc, f1, kw[(e1 & 31) * GROUPS + g]);
                fma4(acc, f2, kw[(e2 & 31) * GROUPS + g]);
                fma4(acc, f3, kw[(e3 & 31) * GROUPS + g]);
            }
            out4[(size_t)rows[lo] * GROUPS + g] = acc;
        }
    }
}

// ---- Last-resort fallback: atomic scatter -----------------------------------
__global__ void mink_conv_scatter(const int* __restrict__ coords,
                                  const int* __restrict__ in_idx,
                                  const int* __restrict__ out_idx,
                                  const float4* __restrict__ in_feats4,
                                  const float4* __restrict__ kernel4,
                                  float* __restrict__ out,
                                  int E) {
    __shared__ float4 kwf[KVOL * GROUPS];
    for (int i = threadIdx.x; i < KVOL * GROUPS; i += blockDim.x)
        kwf[i] = kernel4[i];
    __syncthreads();
    int t = blockIdx.x * blockDim.x + threadIdx.x;
    if (t >= E * GROUPS) return;
    int e = t >> 3, g = t & 7;
    int vi = in_idx[e], vo = out_idx[e];
    int c0 = coords[vi * 3 + 0] - coords[vo * 3 + 0] + 1;
    int c1 = coords[vi * 3 + 1] - coords[vo * 3 + 1] + 1;
    int c2 = coords[vi * 3 + 2] - coords[vo * 3 + 2] + 1;
    int k1d = (c0 * 3 + c1) * 3 + c2;
    float4 f = in_feats4[vi * GROUPS + g];
    float4 w = kwf[k1d * GROUPS + g];
    float* o = out + vo * NCH + g * 4;
    atomicAdd(o + 0, f.x * w.x);
    atomicAdd(o + 1, f.y * w.y);
    atomicAdd(o + 2, f.z * w.z);
    atomicAdd(o + 3, f.w * w.w);
}

static inline size_t align256(size_t x) { return (x + 255) & ~(size_t)255; }

extern "C" void kernel_launch(void* const* d_in, const int* in_sizes, int n_in,
                              void* d_out, int out_size, void* d_ws, size_t ws_size,
                              hipStream_t stream) {
    const int*   coords   = (const int*)d_in[0];
    const int*   in_idx   = (const int*)d_in[1];
    const int*   out_idx  = (const int*)d_in[2];
    const float* in_feats = (const float*)d_in[3];
    const float* kernel   = (const float*)d_in[4];

    const int E     = in_sizes[1];
    const int Nrows = out_size / NCH;

    const size_t dense_bytes = (size_t)LP * LP * LP * sizeof(int); // 4.25 MB

    // Arena capacities (statistical bounds with >>10-sigma margins; tap bound
    // E + 7*Nrows is a hard worst case for pad-to-8)
    int rowcap = Nrows / ARENAS + 1024;
    int tapcap = ((E + 7 * Nrows) / ARENAS + 8192) & ~7;   // mult of 8 (int4 align)

    size_t o_dense  = 0;
    size_t o_gctr   = align256(o_dense + dense_bytes);
    size_t gctr_b   = (size_t)ARENAS * GSTR * sizeof(unsigned long long); // 8 KB
    size_t o_rows   = align256(o_gctr + gctr_b);
    size_t o_offcnt = align256(o_rows + (size_t)ARENAS * rowcap * 4);
    size_t o_list   = align256(o_offcnt + (size_t)ARENAS * rowcap * 4);
    size_t need2    = o_list + (size_t)ARENAS * tapcap * 4;

    char* ws = (char*)d_ws;

    if (ws_size >= need2) {
        int* dense  = (int*)(ws + o_dense);
        unsigned long long* gctr = (unsigned long long*)(ws + o_gctr);
        int* rows_g = (int*)(ws + o_rows);
        int* offcnt = (int*)(ws + o_offcnt);
        int* list_g = (int*)(ws + o_list);

        hipMemsetAsync(dense, 0, dense_bytes, stream);
        hipMemsetAsync(gctr, 0, gctr_b, stream);

        int block = 256;
        int grid1 = (Nrows + block - 1) / block;
        build_dense<<<grid1, block, 0, stream>>>(coords, dense, Nrows);

        compact_region<<<NREGIONS, 256, 0, stream>>>(
            dense, gctr, rows_g, offcnt, list_g, rowcap, tapcap);

        dim3 grid3((rowcap + SLOTS - 1) / SLOTS, ARENAS);
        gather_flat<<<grid3, 256, 0, stream>>>(
            gctr, rows_g, offcnt, list_g,
            (const float4*)in_feats, (const float4*)kernel,
            (float4*)d_out, rowcap, tapcap);
    } else if (ws_size >= dense_bytes) {
        int* dense = (int*)d_ws;
        hipMemsetAsync(dense, 0, dense_bytes, stream);
        int block = 256;
        int grid1 = (Nrows + block - 1) / block;
        build_dense<<<grid1, block, 0, stream>>>(coords, dense, Nrows);
        gather_conv_region<<<NREGIONS, 256, 0, stream>>>(
            dense, (const float4*)in_feats, (const float4*)kernel,
            (float4*)d_out);
    } else {
        hipMemsetAsync(d_out, 0, (size_t)out_size * sizeof(float), stream);
        int total = E * GROUPS;
        int block = 256;
        int grid  = (total + block - 1) / block;
        mink_conv_scatter<<<grid, block, 0, stream>>>(
            coords, in_idx, out_idx,
            (const float4*)in_feats, (const float4*)kernel,
            (float*)d_out, E);
    }
}